// Round 1
// baseline (509.827 us; speedup 1.0000x reference)
//
#include <hip/hip_runtime.h>

typedef unsigned short u16;
typedef __attribute__((ext_vector_type(8))) short s8frag;   // 8 bf16 (4 VGPRs)
typedef __attribute__((ext_vector_type(4))) float f32x4;    // MFMA accumulator

#define GLOAD16(gp, lp)                                                        \
  __builtin_amdgcn_global_load_lds(                                            \
      (const __attribute__((address_space(1))) void*)(gp),                     \
      (__attribute__((address_space(3))) void*)(lp), 16, 0, 0)

__device__ __forceinline__ u16 f2bf(float x) {
  unsigned int u = __float_as_uint(x);
  unsigned int r = (u + 0x7fffu + ((u >> 16) & 1u)) >> 16;  // RNE
  return (u16)r;
}

// ---------------------------------------------------------------------------
// Kernel 1: fold BN into 1x1-conv weights, convert to bf16; fused bias (fp32).
//   w'[o][c] = w[o][c] * gamma[o]/sqrt(var[o]+eps)
//   bias'[o] = scale[o]*(b[o]-mean[o]) + beta[o]
// ---------------------------------------------------------------------------
__global__ __launch_bounds__(256) void prep_w(
    const float* __restrict__ w, const float* __restrict__ b,
    const float* __restrict__ gamma, const float* __restrict__ beta,
    const float* __restrict__ mean, const float* __restrict__ var,
    u16* __restrict__ wout, float* __restrict__ biasout) {
  int idx = blockIdx.x * 256 + threadIdx.x;  // 0 .. 512*512-1
  int o = idx >> 9, c = idx & 511;
  float scale = gamma[o] * rsqrtf(var[o] + 1e-5f);
  wout[idx] = f2bf(w[idx] * scale);
  if (c == 0) biasout[o] = scale * (b[o] - mean[o]) + beta[o];
}

// ---------------------------------------------------------------------------
// Kernel 2: img multi-level sum (upsample-by-(n+1) for lvl>0, edge-pad to 256)
// written TRANSPOSED as bf16:  dst[n][hw][c]  (c contiguous -> GEMM B^T rows)
// Block: 256 thr; tile = (64 c) x (64 w) at fixed (n, h).
// ---------------------------------------------------------------------------
__global__ __launch_bounds__(256) void build_img_t(
    const float* __restrict__ f0, const float* __restrict__ f1,
    const float* __restrict__ f2, const float* __restrict__ f3,
    const float* __restrict__ f4, u16* __restrict__ dst) {
  __shared__ float tile[64][65];
  int t = threadIdx.x;
  int wblk = blockIdx.x;          // 0..3
  int h = blockIdx.y;             // 0..255
  int n = blockIdx.z >> 3;        // 0..1
  int cblk = blockIdx.z & 7;      // 0..7
  int wl = t & 63, w = wblk * 64 + wl;

  const float* feats[5] = {f0, f1, f2, f3, f4};
  const int S[5] = {128, 64, 32, 16, 8};
  int off[5];
#pragma unroll
  for (int l = 0; l < 5; ++l) {
    int s = S[l];
    int scale = (n == 1 && l > 0) ? 2 : 1;
    int u = s * scale, pad = (256 - u) >> 1;
    int ih = h - pad; ih = ih < 0 ? 0 : (ih > u - 1 ? u - 1 : ih); ih /= scale;
    int iw = w - pad; iw = iw < 0 ? 0 : (iw > u - 1 ? u - 1 : iw); iw /= scale;
    off[l] = ih * s + iw;
  }
  int cbase = cblk * 64;
  for (int cs = 0; cs < 16; ++cs) {
    int cl = cs * 4 + (t >> 6);
    int c = cbase + cl;
    float acc = 0.f;
#pragma unroll
    for (int l = 0; l < 5; ++l) {
      int s = S[l];
      acc += feats[l][(long)(n * 512 + c) * s * s + off[l]];
    }
    tile[cl][wl] = acc;
  }
  __syncthreads();
  long hwb = (long)h * 256 + wblk * 64;
#pragma unroll
  for (int half = 0; half < 2; ++half) {
    int c0 = (t & 7) * 8;
    int wl2 = half * 32 + (t >> 3);
    u16 p[8];
#pragma unroll
    for (int j = 0; j < 8; ++j) p[j] = f2bf(tile[c0 + j][wl2]);
    long di = ((long)n * 65536 + hwb + wl2) * 512 + cbase + c0;
    *(uint4*)(dst + di) = *(const uint4*)p;
  }
}

// ---------------------------------------------------------------------------
// Kernel 3: pts NCHW fp32 -> [n][hw][c] bf16 (pure transpose + convert)
// ---------------------------------------------------------------------------
__global__ __launch_bounds__(256) void build_pts_t(
    const float* __restrict__ src, u16* __restrict__ dst) {
  __shared__ float tile[64][65];
  int t = threadIdx.x;
  int wblk = blockIdx.x;
  int h = blockIdx.y;
  int n = blockIdx.z >> 3;
  int cblk = blockIdx.z & 7;
  int wl = t & 63, w = wblk * 64 + wl;
  int cbase = cblk * 64;
  for (int cs = 0; cs < 16; ++cs) {
    int cl = cs * 4 + (t >> 6);
    int c = cbase + cl;
    tile[cl][wl] = src[((long)(n * 512 + c) * 256 + h) * 256 + w];
  }
  __syncthreads();
  long hwb = (long)h * 256 + wblk * 64;
#pragma unroll
  for (int half = 0; half < 2; ++half) {
    int c0 = (t & 7) * 8;
    int wl2 = half * 32 + (t >> 3);
    u16 p[8];
#pragma unroll
    for (int j = 0; j < 8; ++j) p[j] = f2bf(tile[c0 + j][wl2]);
    long di = ((long)n * 65536 + hwb + wl2) * 512 + cbase + c0;
    *(uint4*)(dst + di) = *(const uint4*)p;
  }
}

// ---------------------------------------------------------------------------
// Kernel 4: bf16 MFMA GEMM (m97 structure: 128x128 tile, BK=32, 4 waves,
// global_load_lds width 16, double-buffered LDS, 1 barrier/K-step).
//   Out[n][br*512+o][hw] = relu( sum_c A[o][c]*Bt[n][hw][c] + bias[o] )
// Grid: (1024 col-tiles, 4 row-tiles, 2 branches), block 256.
// ---------------------------------------------------------------------------
__global__ __launch_bounds__(256) void gemm_fused(
    const u16* __restrict__ Aimg, const u16* __restrict__ Apts,
    const u16* __restrict__ Bimg, const u16* __restrict__ Bpts,
    const float* __restrict__ biasImg, const float* __restrict__ biasPts,
    float* __restrict__ out) {
  int br = blockIdx.z;
  const u16* A = br ? Apts : Aimg;
  const u16* B = br ? Bpts : Bimg;
  const float* bias = br ? biasPts : biasImg;

  int ct = blockIdx.x;                 // 0..1023
  int rt = blockIdx.y;                 // 0..3
  int n = ct >> 9;                     // sample
  int colbase = (ct & 511) * 128;      // hw base within sample
  const u16* Bn = B + ((long)n * 65536) * 512;

  __shared__ u16 As[2][128 * 32];
  __shared__ u16 Bs[2][128 * 32];

  int t = threadIdx.x;
  int wave = t >> 6, lane = t & 63;
  int wr = wave >> 1, wc = wave & 1;
  int lrow = lane & 15;
  int lk = (lane >> 4) * 8;            // k sub-offset {0,8,16,24}

  f32x4 acc[4][4] = {};

  // stage K-tile kk into buffer buf (A:128x32, B:128x32; both K-contiguous)
#define STAGE(buf, kk)                                                         \
  {                                                                            \
    _Pragma("unroll") for (int i = 0; i < 2; ++i) {                            \
      int slot = t + i * 256;                                                  \
      int row = slot >> 2, kp = slot & 3;                                      \
      GLOAD16(A + ((long)(rt * 128 + row) * 512 + (kk) + kp * 8),              \
              &As[buf][slot * 8]);                                             \
      GLOAD16(Bn + ((long)(colbase + row) * 512 + (kk) + kp * 8),              \
              &Bs[buf][slot * 8]);                                             \
    }                                                                          \
  }

  STAGE(0, 0);
  __syncthreads();
  int cur = 0;
  for (int kt = 0; kt < 16; ++kt) {
    if (kt < 15) STAGE(cur ^ 1, (kt + 1) * 32);
    s8frag a[4], b[4];
#pragma unroll
    for (int m = 0; m < 4; ++m) {
      int r = wr * 64 + m * 16 + lrow;
      a[m] = *(const s8frag*)&As[cur][r * 32 + lk];
    }
#pragma unroll
    for (int nn = 0; nn < 4; ++nn) {
      int r = wc * 64 + nn * 16 + lrow;
      b[nn] = *(const s8frag*)&Bs[cur][r * 32 + lk];
    }
#pragma unroll
    for (int m = 0; m < 4; ++m)
#pragma unroll
      for (int nn = 0; nn < 4; ++nn)
        acc[m][nn] =
            __builtin_amdgcn_mfma_f32_16x16x32_bf16(a[m], b[nn], acc[m][nn], 0, 0, 0);
    __syncthreads();
    cur ^= 1;
  }
#undef STAGE

  // epilogue: bias + relu, write fp32 NCHW with channel offset br*512
  long outbase = ((long)n * 1024 + br * 512) * 65536;
#pragma unroll
  for (int m = 0; m < 4; ++m) {
    int o0 = rt * 128 + wr * 64 + m * 16 + (lane >> 4) * 4;
#pragma unroll
    for (int nn = 0; nn < 4; ++nn) {
      int hw = colbase + wc * 64 + nn * 16 + (lane & 15);
#pragma unroll
      for (int j = 0; j < 4; ++j) {
        int o = o0 + j;
        float v = acc[m][nn][j] + bias[o];
        v = v > 0.f ? v : 0.f;
        out[outbase + (long)o * 65536 + hw] = v;
      }
    }
  }
}

// ---------------------------------------------------------------------------
extern "C" void kernel_launch(void* const* d_in, const int* in_sizes, int n_in,
                              void* d_out, int out_size, void* d_ws,
                              size_t ws_size, hipStream_t stream) {
  (void)in_sizes; (void)n_in; (void)out_size; (void)ws_size;
  const float* f0 = (const float*)d_in[0];
  const float* f1 = (const float*)d_in[1];
  const float* f2 = (const float*)d_in[2];
  const float* f3 = (const float*)d_in[3];
  const float* f4 = (const float*)d_in[4];
  const float* pts = (const float*)d_in[5];
  const float* img_w = (const float*)d_in[6];
  const float* img_b = (const float*)d_in[7];
  const float* img_gamma = (const float*)d_in[8];
  const float* img_beta = (const float*)d_in[9];
  const float* img_mean = (const float*)d_in[10];
  const float* img_var = (const float*)d_in[11];
  const float* pts_w = (const float*)d_in[12];
  const float* pts_b = (const float*)d_in[13];
  const float* pts_gamma = (const float*)d_in[14];
  const float* pts_beta = (const float*)d_in[15];
  const float* pts_mean = (const float*)d_in[16];
  const float* pts_var = (const float*)d_in[17];

  char* ws = (char*)d_ws;
  u16* wA_img = (u16*)ws;                          // 512*512 bf16 = 512 KiB
  u16* wA_pts = wA_img + 512 * 512;                // 512 KiB
  float* bias_img = (float*)(ws + (1u << 20));     // 2 KiB
  float* bias_pts = bias_img + 512;
  u16* Bimg = (u16*)(ws + (2u << 20));             // 2*65536*512 bf16 = 128 MiB
  u16* Bpts = Bimg + (size_t)2 * 65536 * 512;      // 128 MiB

  prep_w<<<1024, 256, 0, stream>>>(img_w, img_b, img_gamma, img_beta, img_mean,
                                   img_var, wA_img, bias_img);
  prep_w<<<1024, 256, 0, stream>>>(pts_w, pts_b, pts_gamma, pts_beta, pts_mean,
                                   pts_var, wA_pts, bias_pts);
  build_img_t<<<dim3(4, 256, 16), 256, 0, stream>>>(f0, f1, f2, f3, f4, Bimg);
  build_pts_t<<<dim3(4, 256, 16), 256, 0, stream>>>(pts, Bpts);
  gemm_fused<<<dim3(1024, 4, 2), 256, 0, stream>>>(
      wA_img, wA_pts, Bimg, Bpts, bias_img, bias_pts, (float*)d_out);
}